// Round 9
// baseline (589.758 us; speedup 1.0000x reference)
//
#include <hip/hip_runtime.h>
#include <hip/hip_bf16.h>
#include <math.h>

#define N_NODES 50000
#define F_IN    500
#define HEADS   8
#define HID     16
#define HH      128   // HEADS*HID
#define NCLS    40
#define NEG     0.2f

typedef _Float16 f16x2 __attribute__((ext_vector_type(2)));
typedef _Float16 f16x4 __attribute__((ext_vector_type(4)));
typedef _Float16 f16x8 __attribute__((ext_vector_type(8)));
typedef float    f32x4 __attribute__((ext_vector_type(4)));

__device__ __forceinline__ float lrelu(float x) { return x >= 0.f ? x : NEG * x; }

// -------- prep: Wt[128][512] fp16 (K-padded)  +  W2t[64][128] fp32 (row-padded) --------
__global__ void prep_kernel(const float* __restrict__ W1, const float* __restrict__ W2,
                            _Float16* __restrict__ Wt, float* __restrict__ W2t) {
    int i = blockIdx.x * 256 + threadIdx.x;
    if (i < 128 * 512) {
        int c = i >> 9, k = i & 511;
        Wt[i] = (k < F_IN) ? (_Float16)W1[k * HH + c] : (_Float16)0.f;
    }
    int j = i - 128 * 512;
    if (j >= 0 && j < 64 * HH) {
        int c = j >> 7, k = j & 127;
        W2t[j] = (c < NCLS) ? W2[k * NCLS + c] : 0.f;
    }
}

// ---------------- GEMM1 (MFMA fp16): h1h[N,128] = fp16(x[N,500] @ W1) ----------------
// A-path: direct-from-global fragments with DEPTH-2 ping-pong register prefetch
// (explicit macro steps -> all register indices static). B staged in LDS per K-tile.
#define LDPB 136   // padded B row stride (halves)

__global__ __launch_bounds__(256) void gemm1_mfma(const float* __restrict__ x,
                                                  const _Float16* __restrict__ Wt,
                                                  _Float16* __restrict__ h1h) {
    __shared__ _Float16 Bs[128 * LDPB];
    const int t = threadIdx.x;
    const int lane = t & 63, w = t >> 6;
    const int rowBase = blockIdx.x * 64;
    const int arow = rowBase + 16 * w + (lane & 15);
    const bool rowok = arow < N_NODES;
    const int klo = (lane >> 4) * 8;          // 0,8,16,24
    const float* xrow = x + (size_t)arow * F_IN;

    f32x4 acc[8];
#pragma unroll
    for (int n = 0; n < 8; ++n) acc[n] = (f32x4){0.f, 0.f, 0.f, 0.f};

    const int gb = t & 15, cb = t >> 4;       // B staging indices

    float4 A0[8], A1[8];                      // two prefetch buffers (4 ks x 2 halves)

#define LOADA(DST, KT)                                                              \
    {                                                                               \
        _Pragma("unroll")                                                           \
        for (int ks = 0; ks < 4; ++ks) {                                            \
            int kk = (KT) * 128 + ks * 32 + klo;                                    \
            DST[2 * ks]     = (rowok && kk < F_IN)     ? *(const float4*)&xrow[kk]  \
                                                       : make_float4(0, 0, 0, 0);   \
            DST[2 * ks + 1] = (rowok && kk + 4 < F_IN) ? *(const float4*)&xrow[kk + 4] \
                                                       : make_float4(0, 0, 0, 0);   \
        }                                                                           \
    }

#define GSTEP(KT, CUR, DOPREF)                                                      \
    {                                                                               \
        _Pragma("unroll")                                                           \
        for (int p = 0; p < 8; ++p) {                                               \
            int c = cb + 16 * p;                                                    \
            *(f16x8*)&Bs[c * LDPB + 8 * gb] =                                       \
                *(const f16x8*)&Wt[c * 512 + (KT) * 128 + 8 * gb];                  \
        }                                                                           \
        __syncthreads();                                                            \
        f16x8 afr[4];                                                               \
        _Pragma("unroll")                                                           \
        for (int ks = 0; ks < 4; ++ks) {                                            \
            float4 a0 = CUR[2 * ks], a1 = CUR[2 * ks + 1];                          \
            afr[ks] = (f16x8){(_Float16)a0.x, (_Float16)a0.y, (_Float16)a0.z,       \
                              (_Float16)a0.w, (_Float16)a1.x, (_Float16)a1.y,       \
                              (_Float16)a1.z, (_Float16)a1.w};                      \
        }                                                                           \
        if (DOPREF) LOADA(CUR, (KT) + 2);                                           \
        _Pragma("unroll")                                                           \
        for (int ks = 0; ks < 4; ++ks) {                                            \
            _Pragma("unroll")                                                       \
            for (int n = 0; n < 8; ++n) {                                           \
                f16x8 b = *(const f16x8*)&Bs[(16 * n + (lane & 15)) * LDPB +        \
                                             ks * 32 + klo];                        \
                acc[n] = __builtin_amdgcn_mfma_f32_16x16x32_f16(afr[ks], b,         \
                                                                acc[n], 0, 0, 0);   \
            }                                                                       \
        }                                                                           \
        __syncthreads();                                                            \
    }

    LOADA(A0, 0)
    LOADA(A1, 1)
    GSTEP(0, A0, true)
    GSTEP(1, A1, true)
    GSTEP(2, A0, false)
    GSTEP(3, A1, false)

#undef GSTEP
#undef LOADA

    // epilogue: D layout col=lane&15, row=(lane>>4)*4+reg
    const int colb = lane & 15, rq = lane >> 4;
#pragma unroll
    for (int n = 0; n < 8; ++n) {
#pragma unroll
        for (int r = 0; r < 4; ++r) {
            int grow = rowBase + 16 * w + rq * 4 + r;
            if (grow < N_NODES) h1h[(size_t)grow * HH + 16 * n + colb] = (_Float16)acc[n][r];
        }
    }
}

// ---------------- per-node attention coefficients, layer 1 (fp16 h) ----------------
__global__ void alpha1_kernel(const _Float16* __restrict__ h1h,
                              const float* __restrict__ a_src,
                              const float* __restrict__ a_dst,
                              float* __restrict__ asrc, float* __restrict__ adst) {
    int idx = blockIdx.x * blockDim.x + threadIdx.x;
    if (idx >= N_NODES * HEADS) return;
    int n = idx >> 3, h = idx & 7;
    const f16x8* hp = (const f16x8*)&h1h[(size_t)n * HH + h * HID];
    float s = 0.f, d = 0.f;
#pragma unroll
    for (int c = 0; c < 2; ++c) {
        f16x8 hv = hp[c];
#pragma unroll
        for (int i = 0; i < 8; ++i) {
            float f = (float)hv[i];
            s += f * a_src[h * HID + c * 8 + i];
            d += f * a_dst[h * HID + c * 8 + i];
        }
    }
    asrc[idx] = s;
    adst[idx] = d;
}

// ---------------- CSR build ----------------
__global__ void count_kernel(const int* __restrict__ ei, int* __restrict__ deg,
                             int E, int EP) {
    int e = blockIdx.x * blockDim.x + threadIdx.x;
    if (e >= EP) return;
    int dst = (e < E) ? ei[E + e] : (e - E);
    atomicAdd(&deg[dst], 1);
}

__global__ __launch_bounds__(256) void scan1_kernel(const int* __restrict__ deg,
                                                    int* __restrict__ offs,
                                                    int* __restrict__ bsums, int n) {
    __shared__ int sm[256];
    int tid = threadIdx.x, i = blockIdx.x * 256 + tid;
    int v = (i < n) ? deg[i] : 0;
    sm[tid] = v;
    __syncthreads();
    for (int off = 1; off < 256; off <<= 1) {
        int t = 0;
        if (tid >= off) t = sm[tid - off];
        __syncthreads();
        if (tid >= off) sm[tid] += t;
        __syncthreads();
    }
    if (i < n) offs[i] = sm[tid] - v;
    if (tid == 255) bsums[blockIdx.x] = sm[255];
}

__global__ __launch_bounds__(256) void scan2_kernel(const int* __restrict__ bsums,
                                                    int* __restrict__ boffs, int nb,
                                                    int* __restrict__ offs, int n) {
    __shared__ int sm[256];
    int tid = threadIdx.x;
    int v = (tid < nb) ? bsums[tid] : 0;
    sm[tid] = v;
    __syncthreads();
    for (int off = 1; off < 256; off <<= 1) {
        int t = 0;
        if (tid >= off) t = sm[tid - off];
        __syncthreads();
        if (tid >= off) sm[tid] += t;
        __syncthreads();
    }
    if (tid < nb) boffs[tid] = sm[tid] - v;
    if (tid == 255) offs[n] = sm[255];
}

__global__ __launch_bounds__(256) void scan3_kernel(int* __restrict__ offs,
                                                    int* __restrict__ cursor,
                                                    const int* __restrict__ boffs, int n) {
    int i = blockIdx.x * 256 + threadIdx.x;
    if (i >= n) return;
    int o = offs[i] + boffs[blockIdx.x];
    offs[i] = o;
    cursor[i] = o;
}

__global__ void fill_kernel(const int* __restrict__ ei, int* __restrict__ cursor,
                            int* __restrict__ bsrc, int E, int EP) {
    int e = blockIdx.x * blockDim.x + threadIdx.x;
    if (e >= EP) return;
    int src, dst;
    if (e < E) { src = ei[e]; dst = ei[E + e]; }
    else       { src = e - E; dst = e - E; }
    int slot = atomicAdd(&cursor[dst], 1);
    bsrc[slot] = src;
}

// ------- layer-1 aggregation: wave/node, single pass, 4-deep unroll -------
__global__ __launch_bounds__(256) void agg1_kernel(const _Float16* __restrict__ h1h,
                                                   const float* __restrict__ asrc,
                                                   const float* __restrict__ adst,
                                                   const int* __restrict__ offs,
                                                   const int* __restrict__ bsrc,
                                                   const float* __restrict__ b1,
                                                   _Float16* __restrict__ h1bh) {
    int lane = threadIdx.x & 63;
    int node = blockIdx.x * 4 + (threadIdx.x >> 6);
    if (node >= N_NODES) return;
    int beg = offs[node], end = offs[node + 1];
    int hh = lane >> 3;
    float adv = adst[node * 8 + hh];

    float acc0 = 0.f, acc1 = 0.f, dsum = 0.f;
    int j = beg;
    for (; j + 4 <= end; j += 4) {
        int s0 = bsrc[j], s1 = bsrc[j + 1], s2 = bsrc[j + 2], s3 = bsrc[j + 3];
        float a0 = asrc[s0 * 8 + hh], a1 = asrc[s1 * 8 + hh];
        float a2 = asrc[s2 * 8 + hh], a3 = asrc[s3 * 8 + hh];
        f16x2 h0 = *(const f16x2*)&h1h[(size_t)s0 * HH + 2 * lane];
        f16x2 h1 = *(const f16x2*)&h1h[(size_t)s1 * HH + 2 * lane];
        f16x2 h2 = *(const f16x2*)&h1h[(size_t)s2 * HH + 2 * lane];
        f16x2 h3 = *(const f16x2*)&h1h[(size_t)s3 * HH + 2 * lane];
        float w0 = __expf(lrelu(a0 + adv));
        float w1 = __expf(lrelu(a1 + adv));
        float w2 = __expf(lrelu(a2 + adv));
        float w3 = __expf(lrelu(a3 + adv));
        dsum += (w0 + w1) + (w2 + w3);
        acc0 += w0 * (float)h0[0] + w1 * (float)h1[0] + w2 * (float)h2[0] + w3 * (float)h3[0];
        acc1 += w0 * (float)h0[1] + w1 * (float)h1[1] + w2 * (float)h2[1] + w3 * (float)h3[1];
    }
    for (; j < end; ++j) {
        int s0 = bsrc[j];
        float a0 = asrc[s0 * 8 + hh];
        f16x2 h0 = *(const f16x2*)&h1h[(size_t)s0 * HH + 2 * lane];
        float w0 = __expf(lrelu(a0 + adv));
        dsum += w0;
        acc0 += w0 * (float)h0[0];
        acc1 += w0 * (float)h0[1];
    }
    float rv = 1.f / (dsum + 1e-16f);
    float2 bv = *(const float2*)&b1[2 * lane];
    float v0 = acc0 * rv + bv.x;
    float v1 = acc1 * rv + bv.y;
    v0 = v0 > 0.f ? v0 : __expf(v0) - 1.f;   // ELU
    v1 = v1 > 0.f ? v1 : __expf(v1) - 1.f;
    f16x2 o = {(_Float16)v0, (_Float16)v1};
    *(f16x2*)&h1bh[(size_t)node * HH + 2 * lane] = o;
}

// ---- fused GEMM2 + alpha2: one wave per node ----
// h2[c] = dot(h1b[node,:], W2t[c,:]) ; asrc2/adst2 via in-wave shuffle reduce.
__global__ __launch_bounds__(256) void gemm2b_kernel(const _Float16* __restrict__ h1bh,
                                                     const float* __restrict__ W2t,
                                                     const float* __restrict__ a_src2,
                                                     const float* __restrict__ a_dst2,
                                                     _Float16* __restrict__ h2h,
                                                     float* __restrict__ asrc2,
                                                     float* __restrict__ adst2) {
    int lane = threadIdx.x & 63;
    int node = blockIdx.x * 4 + (threadIdx.x >> 6);
    if (node >= N_NODES) return;
    const f16x8* hp = (const f16x8*)&h1bh[(size_t)node * HH];
    const float* wrow = W2t + lane * HH;          // rows 40..63 are zero-padded
    float acc = 0.f;
#pragma unroll
    for (int i = 0; i < 16; ++i) {
        f16x8 hv = hp[i];                          // broadcast load (same addr all lanes)
#pragma unroll
        for (int q = 0; q < 8; ++q)
            acc += (float)hv[q] * wrow[i * 8 + q];
    }
    bool act = lane < NCLS;
    if (act) h2h[(size_t)node * NCLS + lane] = (_Float16)acc;
    float ps = act ? acc * a_src2[lane] : 0.f;
    float pd = act ? acc * a_dst2[lane] : 0.f;
#pragma unroll
    for (int o = 32; o; o >>= 1) {
        ps += __shfl_xor(ps, o, 64);
        pd += __shfl_xor(pd, o, 64);
    }
    if (lane == 0) {
        asrc2[node] = ps;
        adst2[node] = pd;
    }
}

// ------- layer-2 aggregation, single pass, 4-deep unroll, fused log_softmax -------
__global__ __launch_bounds__(256) void agg2_kernel(const _Float16* __restrict__ h2h,
                                                   const float* __restrict__ asrc,
                                                   const float* __restrict__ adst,
                                                   const int* __restrict__ offs,
                                                   const int* __restrict__ bsrc,
                                                   const float* __restrict__ b2,
                                                   float* __restrict__ out) {
    int lane = threadIdx.x & 63;
    int node = blockIdx.x * 4 + (threadIdx.x >> 6);
    if (node >= N_NODES) return;
    int beg = offs[node], end = offs[node + 1];
    float adv = adst[node];
    bool act = lane < NCLS / 2;

    float acc0 = 0.f, acc1 = 0.f, dsum = 0.f;
    int j = beg;
    for (; j + 4 <= end; j += 4) {
        int s0 = bsrc[j], s1 = bsrc[j + 1], s2 = bsrc[j + 2], s3 = bsrc[j + 3];
        float w0 = __expf(lrelu(asrc[s0] + adv));
        float w1 = __expf(lrelu(asrc[s1] + adv));
        float w2 = __expf(lrelu(asrc[s2] + adv));
        float w3 = __expf(lrelu(asrc[s3] + adv));
        f16x2 h0 = {(_Float16)0.f, (_Float16)0.f}, h1 = h0, h2 = h0, h3 = h0;
        if (act) {
            h0 = *(const f16x2*)&h2h[(size_t)s0 * NCLS + 2 * lane];
            h1 = *(const f16x2*)&h2h[(size_t)s1 * NCLS + 2 * lane];
            h2 = *(const f16x2*)&h2h[(size_t)s2 * NCLS + 2 * lane];
            h3 = *(const f16x2*)&h2h[(size_t)s3 * NCLS + 2 * lane];
        }
        dsum += (w0 + w1) + (w2 + w3);
        acc0 += w0 * (float)h0[0] + w1 * (float)h1[0] + w2 * (float)h2[0] + w3 * (float)h3[0];
        acc1 += w0 * (float)h0[1] + w1 * (float)h1[1] + w2 * (float)h2[1] + w3 * (float)h3[1];
    }
    for (; j < end; ++j) {
        int s0 = bsrc[j];
        float w0 = __expf(lrelu(asrc[s0] + adv));
        f16x2 h0 = {(_Float16)0.f, (_Float16)0.f};
        if (act) h0 = *(const f16x2*)&h2h[(size_t)s0 * NCLS + 2 * lane];
        dsum += w0;
        acc0 += w0 * (float)h0[0];
        acc1 += w0 * (float)h0[1];
    }
    float rd = 1.f / (dsum + 1e-16f);
    float v0 = -1e30f, v1 = -1e30f;
    if (act) {
        float2 bv = *(const float2*)&b2[2 * lane];
        v0 = acc0 * rd + bv.x;
        v1 = acc1 * rd + bv.y;
    }
    float m = fmaxf(v0, v1);
#pragma unroll
    for (int o = 32; o; o >>= 1) m = fmaxf(m, __shfl_xor(m, o, 64));
    float p = act ? (__expf(v0 - m) + __expf(v1 - m)) : 0.f;
#pragma unroll
    for (int o = 32; o; o >>= 1) p += __shfl_xor(p, o, 64);
    float ls = m + __logf(p);
    if (act) {
        float2 ov = make_float2(v0 - ls, v1 - ls);
        *(float2*)&out[(size_t)node * NCLS + 2 * lane] = ov;
    }
}

extern "C" void kernel_launch(void* const* d_in, const int* in_sizes, int n_in,
                              void* d_out, int out_size, void* d_ws, size_t ws_size,
                              hipStream_t stream) {
    const float* x      = (const float*)d_in[0];
    const int*   ei     = (const int*)d_in[1];
    const float* W1     = (const float*)d_in[2];
    const float* a_src1 = (const float*)d_in[3];
    const float* a_dst1 = (const float*)d_in[4];
    const float* b1     = (const float*)d_in[5];
    const float* W2     = (const float*)d_in[6];
    const float* a_src2 = (const float*)d_in[7];
    const float* a_dst2 = (const float*)d_in[8];
    const float* b2     = (const float*)d_in[9];
    float* out = (float*)d_out;

    const int E  = in_sizes[1] / 2;
    const int EP = E + N_NODES;
    const int NB = (N_NODES + 255) / 256;

    char* w = (char*)d_ws;
    _Float16* h1h   = (_Float16*)(w + 0);          // 12,800,000 B
    _Float16* h1bh  = (_Float16*)(w + 12800000);   // 12,800,000 B
    float*    asrc1 = (float*)(w + 25600000);      //  1,600,000 B
    float*    adst1 = (float*)(w + 27200000);      //  1,600,000 B
    _Float16* h2h   = (_Float16*)(w + 28800000);   //  4,000,000 B
    float*    asrc2 = (float*)(w + 32800000);      //    200,000 B
    float*    adst2 = (float*)(w + 33000000);      //    200,000 B
    int*      deg   = (int*)(w + 33200000);        //    200,000 B
    int*      offs  = (int*)(w + 33400064);        //    200,004 B
    int*      cursor= (int*)(w + 33600128);        //    200,000 B
    int*      bsrc  = (int*)(w + 33800192);        //  3,400,000 B
    _Float16* Wt    = (_Float16*)(w + 37200256);   //    131,072 B
    int*      bsums = (int*)(w + 37331328);        //      1,024 B
    int*      boffs = (int*)(w + 37332352);        //      1,024 B
    float*    W2t   = (float*)(w + 37333376);      //     32,768 B (end ~37.4 MB)

    hipMemsetAsync(deg, 0, N_NODES * sizeof(int), stream);
    prep_kernel<<<(128 * 512 + 64 * HH + 255) / 256, 256, 0, stream>>>(W1, W2, Wt, W2t);
    gemm1_mfma<<<(N_NODES + 63) / 64, 256, 0, stream>>>(x, Wt, h1h);
    alpha1_kernel<<<(N_NODES * HEADS + 255) / 256, 256, 0, stream>>>(h1h, a_src1, a_dst1,
                                                                     asrc1, adst1);
    count_kernel<<<(EP + 255) / 256, 256, 0, stream>>>(ei, deg, E, EP);
    scan1_kernel<<<NB, 256, 0, stream>>>(deg, offs, bsums, N_NODES);
    scan2_kernel<<<1, 256, 0, stream>>>(bsums, boffs, NB, offs, N_NODES);
    scan3_kernel<<<NB, 256, 0, stream>>>(offs, cursor, boffs, N_NODES);
    fill_kernel<<<(EP + 255) / 256, 256, 0, stream>>>(ei, cursor, bsrc, E, EP);
    agg1_kernel<<<(N_NODES + 3) / 4, 256, 0, stream>>>(h1h, asrc1, adst1, offs, bsrc, b1, h1bh);
    gemm2b_kernel<<<(N_NODES + 3) / 4, 256, 0, stream>>>(h1bh, W2t, a_src2, a_dst2,
                                                         h2h, asrc2, adst2);
    agg2_kernel<<<(N_NODES + 3) / 4, 256, 0, stream>>>(h2h, asrc2, adst2, offs, bsrc, b2, out);
}